// Round 6
// baseline (193.059 us; speedup 1.0000x reference)
//
#include <hip/hip_runtime.h>
#include <stdint.h>

typedef __attribute__((ext_vector_type(8))) unsigned short ushort8v;
typedef __attribute__((ext_vector_type(8))) short bf16x8;
typedef __attribute__((ext_vector_type(4))) float f32x4;
typedef __attribute__((ext_vector_type(2))) float f32x2;
typedef __attribute__((ext_vector_type(4))) unsigned int uint4v;

__device__ __forceinline__ float bf2f(unsigned short u) {
    return __uint_as_float(((unsigned)u) << 16);
}
__device__ __forceinline__ unsigned short f2bf(float f) {
    unsigned u = __float_as_uint(f);
    unsigned r = u + 0x7fffu + ((u >> 16) & 1u);   // RNE
    return (unsigned short)(r >> 16);
}
__device__ __forceinline__ unsigned cvt_pk_bf16(float lo, float hi) {
    unsigned r;
    asm("v_cvt_pk_bf16_f32 %0, %1, %2" : "=v"(r) : "v"(lo), "v"(hi));
    return r;
}
// unpack a bf16-pair word to two f32 (lo = <<16, hi = mask) — 2 VALU ops
__device__ __forceinline__ f32x2 up2(unsigned u) {
    f32x2 r;
    r[0] = __uint_as_float(u << 16);
    r[1] = __uint_as_float(u & 0xffff0000u);
    return r;
}

// ---------------- pre-pass 1: planes (3 x [32][256][256] f32) -> [3][y][x][c] bf16
__global__ __launch_bounds__(256) void transpose_planes_kernel(
    const float* __restrict__ pxy, const float* __restrict__ pxz,
    const float* __restrict__ pyz, unsigned int* __restrict__ tp)
{
    __shared__ unsigned int lt[64 * 17];   // [yx][c2], pad 17 kills bank conflicts
    const int bid = blockIdx.x;
    const int plane = bid >> 10;           // 1024 blocks per plane
    const int base = (bid & 1023) * 64;    // 64 pixels per block
    const float* __restrict__ src = plane == 0 ? pxy : (plane == 1 ? pxz : pyz);
    const int tid = threadIdx.x;
    {
        const int c2 = tid >> 4;           // channel pair 0..15
        const int s  = tid & 15;           // pixel group (4 px)
        const f32x4 va = *(const f32x4*)(src + (size_t)(2 * c2)     * 65536 + base + 4 * s);
        const f32x4 vb = *(const f32x4*)(src + (size_t)(2 * c2 + 1) * 65536 + base + 4 * s);
        #pragma unroll
        for (int j = 0; j < 4; ++j) {
            int yx = 4 * s + j;
            lt[yx * 17 + c2] = ((unsigned)f2bf(vb[j]) << 16) | (unsigned)f2bf(va[j]);
        }
    }
    __syncthreads();
    {
        const int yx = tid >> 2, q = tid & 3;
        uint4v o;
        #pragma unroll
        for (int k = 0; k < 4; ++k) o[k] = lt[yx * 17 + 4 * q + k];
        *(uint4v*)(tp + ((size_t)plane * 65536 + base + yx) * 16 + 4 * q) = o;
    }
}

// ---------------- pre-pass 2: pack MLP weights (transposed) into swizzled MFMA A-frag layout
// lane l's 16B at slot (l ^ (l>>3)); lane l holds A[mt*16+(l&15)][kc*32+(l>>4)*8+j].
__global__ __launch_bounds__(256) void pack_weights_kernel(
    const float* __restrict__ w1, const float* __restrict__ w2,
    const float* __restrict__ wc1, const float* __restrict__ wc2,
    const float* __restrict__ wc3, unsigned int* __restrict__ pack)
{
    int t = blockIdx.x * 256 + threadIdx.x;
    if (t >= 28 * 64) return;
    int lane = t & 63, tile = t >> 6;
    int mat, mt, kc;
    if (tile < 12)      { mat = 0; kc = tile >> 2;        mt = tile & 3; }
    else if (tile < 14) { mat = 1; kc = tile - 12;        mt = 0; }
    else if (tile < 18) { mat = 2; kc = 0;                mt = tile - 14; }
    else if (tile < 26) { mat = 3; kc = (tile - 18) >> 2; mt = (tile - 18) & 3; }
    else                { mat = 4; kc = tile - 26;        mt = 0; }
    int of = mt * 16 + (lane & 15);
    int kb = kc * 32 + (lane >> 4) * 8;
    float f[8];
    #pragma unroll
    for (int j = 0; j < 8; ++j) {
        int k = kb + j;
        float v;
        if (mat == 0)      v = w1[k * 64 + of];
        else if (mat == 1) v = w2[k * 16 + of];
        else if (mat == 2) v = (k >= 1 && k < 16) ? wc1[(k - 1) * 64 + of] : 0.0f;
        else if (mat == 3) v = wc2[k * 64 + of];
        else               v = (of < 3) ? wc3[k * 3 + of] : 0.0f;
        f[j] = v;
    }
    int sl = lane ^ (lane >> 3);
    unsigned int* dst = pack + tile * 256 + sl * 4;
    #pragma unroll
    for (int w = 0; w < 4; ++w)
        dst[w] = ((unsigned)f2bf(f[2 * w + 1]) << 16) | (unsigned)f2bf(f[2 * w]);
}

// ---------------- main: 2 wave-tiles (32 points) per wave, interleaved for ILP.
// A-frag ds_reads shared across the pair; gathers batched per plane (8 in flight).
__global__ __launch_bounds__(512, 4) void nerf_mfma_kernel(
    const float* __restrict__ xin,
    const unsigned short* __restrict__ tp,
    const unsigned int* __restrict__ wpack,
    const float* __restrict__ center, const float* __restrict__ scale,
    float* __restrict__ out, int npts, int nwt)
{
    __shared__ unsigned int wlds[28 * 256];
    const int tid = threadIdx.x;
    #pragma unroll 2
    for (int idx = tid; idx < 28 * 256; idx += 512) wlds[idx] = wpack[idx];
    __syncthreads();

    const int lane = tid & 63;
    const int wv   = tid >> 6;            // 0..7
    const int p    = lane & 15;
    const int G    = lane >> 4;
    const bool hi32 = (lane & 32) != 0;
    const int sl   = lane ^ (lane >> 3);
    const bf16x8* Af = (const bf16x8*)wlds;
    const char* tpB = (const char*)tp;

    const float ctr0 = center[0], ctr1 = center[1], ctr2 = center[2];
    const float sc0 = scale[0], sc1 = scale[1], sc2 = scale[2];

    auto repack64 = [&](const unsigned pk[4][2], int kc2) -> bf16x8 {
        uint4v bw;
        #pragma unroll
        for (int w = 0; w < 4; ++w) {
            int src = p + 16 * (2 * (G & 1) + (w >> 1));
            unsigned lo_ = (unsigned)__shfl((int)pk[2 * kc2][w & 1], src, 64);
            unsigned hi_ = (unsigned)__shfl((int)pk[2 * kc2 + 1][w & 1], src, 64);
            bw[w] = hi32 ? hi_ : lo_;
        }
        return __builtin_bit_cast(bf16x8, bw);
    };

    for (int wtb = blockIdx.x * 16; wtb < nwt; wtb += gridDim.x * 16) {
        asm volatile("" ::: "memory");
        const int wt0 = wtb + wv * 2;
        int gpt[2]; bool valid[2];
        float us[2][3], vs[2][3];
        #pragma unroll
        for (int u = 0; u < 2; ++u) {
            const int wt = wt0 + u;
            gpt[u] = wt * 16 + p;
            valid[u] = (wt < nwt) && (gpt[u] < npts);
            const int rp = valid[u] ? gpt[u] : (npts - 1);
            const float xv = xin[3 * rp + 0], yv = xin[3 * rp + 1], zv = xin[3 * rp + 2];
            auto norm1 = [&](float v, float c, float s) {
                float xn = fminf(fmaxf((v - c) / s + 0.5f, 0.0f), 1.0f);
                return xn * 2.0f - 1.0f;
            };
            const float gx = norm1(xv, ctr0, sc0);
            const float gy = norm1(yv, ctr1, sc1);
            const float gz = norm1(zv, ctr2, sc2);
            us[u][0] = gx; us[u][1] = gx; us[u][2] = gy;
            vs[u][0] = gy; vs[u][1] = gz; vs[u][2] = gz;
        }

        // ---- L1: per plane, gather both tiles (8 loads in flight), interp, shared-frag MFMA
        f32x4 acc1[2][4];
        #pragma unroll
        for (int u = 0; u < 2; ++u)
            #pragma unroll
            for (int mt = 0; mt < 4; ++mt) acc1[u][mt] = f32x4{0.f, 0.f, 0.f, 0.f};

        #pragma unroll
        for (int pl = 0; pl < 3; ++pl) {
            uint4v cv[2][4];
            float wq[2][4];
            #pragma unroll
            for (int u = 0; u < 2; ++u) {
                // px,py in [0,255] exactly (inputs pre-clipped) -> no clamps needed;
                // x1/y1 are +64B / +16KB offsets; boundary over-reads hit allocated ws
                // and carry an exactly-zero bilinear weight.
                float pxf = (us[u][pl] + 1.0f) * 0.5f * 255.0f;
                float pyf = (vs[u][pl] + 1.0f) * 0.5f * 255.0f;
                int x0 = (int)pxf, y0 = (int)pyf;
                float wx = pxf - (float)x0, wy = pyf - (float)y0;
                wq[u][0] = (1.f - wx) * (1.f - wy); wq[u][1] = wx * (1.f - wy);
                wq[u][2] = (1.f - wx) * wy;         wq[u][3] = wx * wy;
                const char* b00 = tpB + (((pl << 16) + (y0 << 8) + x0) << 6) + (G << 4);
                cv[u][0] = *(const uint4v*)(b00);
                cv[u][1] = *(const uint4v*)(b00 + 64);
                cv[u][2] = *(const uint4v*)(b00 + 16384);
                cv[u][3] = *(const uint4v*)(b00 + 16384 + 64);
            }
            bf16x8 bfr[2];
            #pragma unroll
            for (int u = 0; u < 2; ++u) {
                const f32x2 W00 = {wq[u][0], wq[u][0]}, W01 = {wq[u][1], wq[u][1]};
                const f32x2 W10 = {wq[u][2], wq[u][2]}, W11 = {wq[u][3], wq[u][3]};
                uint4v bw;
                #pragma unroll
                for (int w = 0; w < 4; ++w) {
                    f32x2 a = up2(cv[u][0][w]) * W00 + up2(cv[u][1][w]) * W01
                            + up2(cv[u][2][w]) * W10 + up2(cv[u][3][w]) * W11;
                    bw[w] = cvt_pk_bf16(a[0], a[1]);
                }
                bfr[u] = __builtin_bit_cast(bf16x8, bw);
            }
            #pragma unroll
            for (int mt = 0; mt < 4; ++mt) {
                const bf16x8 frag = Af[(pl * 4 + mt) * 64 + sl];
                #pragma unroll
                for (int u = 0; u < 2; ++u)
                    acc1[u][mt] = __builtin_amdgcn_mfma_f32_16x16x32_bf16(
                        frag, bfr[u], acc1[u][mt], 0, 0, 0);
            }
        }

        // ---- repack h (relu); L2: o^T = W2^T @ h^T
        unsigned pk1[2][4][2];
        #pragma unroll
        for (int u = 0; u < 2; ++u)
            #pragma unroll
            for (int mt = 0; mt < 4; ++mt) {
                pk1[u][mt][0] = cvt_pk_bf16(fmaxf(acc1[u][mt][0], 0.f), fmaxf(acc1[u][mt][1], 0.f));
                pk1[u][mt][1] = cvt_pk_bf16(fmaxf(acc1[u][mt][2], 0.f), fmaxf(acc1[u][mt][3], 0.f));
            }
        f32x4 acc2[2];
        #pragma unroll
        for (int u = 0; u < 2; ++u) acc2[u] = f32x4{0.f, 0.f, 0.f, 0.f};
        #pragma unroll
        for (int kc2 = 0; kc2 < 2; ++kc2) {
            bf16x8 b[2];
            #pragma unroll
            for (int u = 0; u < 2; ++u) b[u] = repack64(pk1[u], kc2);
            const bf16x8 frag = Af[(12 + kc2) * 64 + sl];
            #pragma unroll
            for (int u = 0; u < 2; ++u)
                acc2[u] = __builtin_amdgcn_mfma_f32_16x16x32_bf16(frag, b[u], acc2[u], 0, 0, 0);
        }
        #pragma unroll
        for (int u = 0; u < 2; ++u)
            if (valid[u] && lane < 16) out[(size_t)3 * npts + gpt[u]] = acc2[u][0];   // sigma

        // ---- repack o -> b3 (no relu; zero weight row kills sigma term); L3
        bf16x8 b3[2];
        #pragma unroll
        for (int u = 0; u < 2; ++u) {
            unsigned pk2[2];
            pk2[0] = cvt_pk_bf16(acc2[u][0], acc2[u][1]);
            pk2[1] = cvt_pk_bf16(acc2[u][2], acc2[u][3]);
            uint4v bw3;
            #pragma unroll
            for (int w = 0; w < 4; ++w) {
                int src = p + 16 * (2 * (G & 1) + (w >> 1));
                unsigned v = (unsigned)__shfl((int)pk2[w & 1], src, 64);
                bw3[w] = (G < 2) ? v : 0u;
            }
            b3[u] = __builtin_bit_cast(bf16x8, bw3);
        }
        f32x4 acc3[2][4];
        #pragma unroll
        for (int u = 0; u < 2; ++u)
            #pragma unroll
            for (int mt = 0; mt < 4; ++mt) acc3[u][mt] = f32x4{0.f, 0.f, 0.f, 0.f};
        #pragma unroll
        for (int mt = 0; mt < 4; ++mt) {
            const bf16x8 frag = Af[(14 + mt) * 64 + sl];
            #pragma unroll
            for (int u = 0; u < 2; ++u)
                acc3[u][mt] = __builtin_amdgcn_mfma_f32_16x16x32_bf16(frag, b3[u], acc3[u][mt], 0, 0, 0);
        }

        // ---- repack c1 (relu); L4
        unsigned pk3[2][4][2];
        #pragma unroll
        for (int u = 0; u < 2; ++u)
            #pragma unroll
            for (int mt = 0; mt < 4; ++mt) {
                pk3[u][mt][0] = cvt_pk_bf16(fmaxf(acc3[u][mt][0], 0.f), fmaxf(acc3[u][mt][1], 0.f));
                pk3[u][mt][1] = cvt_pk_bf16(fmaxf(acc3[u][mt][2], 0.f), fmaxf(acc3[u][mt][3], 0.f));
            }
        f32x4 acc4[2][4];
        #pragma unroll
        for (int u = 0; u < 2; ++u)
            #pragma unroll
            for (int mt = 0; mt < 4; ++mt) acc4[u][mt] = f32x4{0.f, 0.f, 0.f, 0.f};
        #pragma unroll
        for (int kc2 = 0; kc2 < 2; ++kc2) {
            bf16x8 b[2];
            #pragma unroll
            for (int u = 0; u < 2; ++u) b[u] = repack64(pk3[u], kc2);
            #pragma unroll
            for (int mt = 0; mt < 4; ++mt) {
                const bf16x8 frag = Af[(18 + kc2 * 4 + mt) * 64 + sl];
                #pragma unroll
                for (int u = 0; u < 2; ++u)
                    acc4[u][mt] = __builtin_amdgcn_mfma_f32_16x16x32_bf16(frag, b[u], acc4[u][mt], 0, 0, 0);
            }
        }

        // ---- repack c2 (relu); L5: color^T = Wc3^T @ relu(c2)^T
        unsigned pk4[2][4][2];
        #pragma unroll
        for (int u = 0; u < 2; ++u)
            #pragma unroll
            for (int mt = 0; mt < 4; ++mt) {
                pk4[u][mt][0] = cvt_pk_bf16(fmaxf(acc4[u][mt][0], 0.f), fmaxf(acc4[u][mt][1], 0.f));
                pk4[u][mt][1] = cvt_pk_bf16(fmaxf(acc4[u][mt][2], 0.f), fmaxf(acc4[u][mt][3], 0.f));
            }
        f32x4 acc5[2];
        #pragma unroll
        for (int u = 0; u < 2; ++u) acc5[u] = f32x4{0.f, 0.f, 0.f, 0.f};
        #pragma unroll
        for (int kc2 = 0; kc2 < 2; ++kc2) {
            bf16x8 b[2];
            #pragma unroll
            for (int u = 0; u < 2; ++u) b[u] = repack64(pk4[u], kc2);
            const bf16x8 frag = Af[(26 + kc2) * 64 + sl];
            #pragma unroll
            for (int u = 0; u < 2; ++u)
                acc5[u] = __builtin_amdgcn_mfma_f32_16x16x32_bf16(frag, b[u], acc5[u], 0, 0, 0);
        }
        #pragma unroll
        for (int u = 0; u < 2; ++u)
            if (valid[u] && lane < 16) {
                out[(size_t)3 * gpt[u] + 0] = 1.0f / (1.0f + __expf(-acc5[u][0]));
                out[(size_t)3 * gpt[u] + 1] = 1.0f / (1.0f + __expf(-acc5[u][1]));
                out[(size_t)3 * gpt[u] + 2] = 1.0f / (1.0f + __expf(-acc5[u][2]));
            }
    }
}

// ---------------- fallback (ws too small): pure-VALU kernel, f32 planes
__global__ __launch_bounds__(256) void nerf_fallback_kernel(
    const float* __restrict__ xin,
    const float* __restrict__ pxy, const float* __restrict__ pxz,
    const float* __restrict__ pyz,
    const float* __restrict__ center, const float* __restrict__ scale,
    const float* __restrict__ w1, const float* __restrict__ w2,
    const float* __restrict__ wc1, const float* __restrict__ wc2,
    const float* __restrict__ wc3, float* __restrict__ out, int npts)
{
    __shared__ unsigned short act[64][256];
    const int tid = threadIdx.x;
    const int i = blockIdx.x * 256 + tid;
    if (i >= npts) return;
    const float xv = xin[3 * i], yv = xin[3 * i + 1], zv = xin[3 * i + 2];
    auto norm1 = [&](float v, int k) {
        float xn = fminf(fmaxf((v - center[k]) / scale[k] + 0.5f, 0.0f), 1.0f);
        return xn * 2.0f - 1.0f;
    };
    const float gx = norm1(xv, 0), gy = norm1(yv, 1), gz = norm1(zv, 2);
    float h[64];
    #pragma unroll
    for (int j = 0; j < 64; ++j) h[j] = 0.0f;
    auto samp = [&](float gu, float gv, int pl, const float* __restrict__ splane) {
        float pxf = (gu + 1.0f) * 0.5f * 255.0f, pyf = (gv + 1.0f) * 0.5f * 255.0f;
        float x0f = floorf(pxf), y0f = floorf(pyf);
        float wx = pxf - x0f, wy = pyf - y0f;
        int x0 = min(max((int)x0f, 0), 255), y0 = min(max((int)y0f, 0), 255);
        int x1 = min(x0 + 1, 255), y1 = min(y0 + 1, 255);
        float w00 = (1 - wx) * (1 - wy), w01 = wx * (1 - wy), w10 = (1 - wx) * wy, w11 = wx * wy;
        for (int c = 0; c < 32; ++c) {
            const float* b = splane + (size_t)c * 65536;
            float f = b[y0 * 256 + x0] * w00 + b[y0 * 256 + x1] * w01
                    + b[y1 * 256 + x0] * w10 + b[y1 * 256 + x1] * w11;
            const float* wr = w1 + (size_t)((pl * 32 + c) * 64);
            #pragma unroll
            for (int j = 0; j < 64; ++j) h[j] = fmaf(f, wr[j], h[j]);
        }
    };
    samp(gx, gy, 0, pxy); samp(gx, gz, 1, pxz); samp(gy, gz, 2, pyz);
    #pragma unroll
    for (int j = 0; j < 64; ++j) act[j][tid] = f2bf(fmaxf(h[j], 0.0f));
    float o[16];
    #pragma unroll
    for (int j = 0; j < 16; ++j) o[j] = 0.0f;
    for (int k = 0; k < 64; ++k) {
        float hv = bf2f(act[k][tid]);
        #pragma unroll
        for (int j = 0; j < 16; ++j) o[j] = fmaf(hv, w2[k * 16 + j], o[j]);
    }
    out[(size_t)3 * npts + i] = o[0];
    float c1[64];
    #pragma unroll
    for (int j = 0; j < 64; ++j) c1[j] = 0.0f;
    #pragma unroll
    for (int k = 0; k < 15; ++k)
        #pragma unroll
        for (int j = 0; j < 64; ++j) c1[j] = fmaf(o[k + 1], wc1[k * 64 + j], c1[j]);
    #pragma unroll
    for (int j = 0; j < 64; ++j) act[j][tid] = f2bf(fmaxf(c1[j], 0.0f));
    float c2[64];
    #pragma unroll
    for (int j = 0; j < 64; ++j) c2[j] = 0.0f;
    for (int k = 0; k < 64; ++k) {
        float v = bf2f(act[k][tid]);
        #pragma unroll
        for (int j = 0; j < 64; ++j) c2[j] = fmaf(v, wc2[k * 64 + j], c2[j]);
    }
    float r0 = 0, r1 = 0, r2 = 0;
    #pragma unroll
    for (int k = 0; k < 64; ++k) {
        float v = fmaxf(c2[k], 0.0f);
        r0 = fmaf(v, wc3[k * 3 + 0], r0);
        r1 = fmaf(v, wc3[k * 3 + 1], r1);
        r2 = fmaf(v, wc3[k * 3 + 2], r2);
    }
    out[(size_t)3 * i + 0] = 1.0f / (1.0f + expf(-r0));
    out[(size_t)3 * i + 1] = 1.0f / (1.0f + expf(-r1));
    out[(size_t)3 * i + 2] = 1.0f / (1.0f + expf(-r2));
}

extern "C" void kernel_launch(void* const* d_in, const int* in_sizes, int n_in,
                              void* d_out, int out_size, void* d_ws, size_t ws_size,
                              hipStream_t stream) {
    const float* x      = (const float*)d_in[0];
    const float* pxy    = (const float*)d_in[2];
    const float* pxz    = (const float*)d_in[3];
    const float* pyz    = (const float*)d_in[4];
    const float* center = (const float*)d_in[5];
    const float* scale  = (const float*)d_in[6];
    const float* w1     = (const float*)d_in[7];
    const float* w2     = (const float*)d_in[8];
    const float* wc1    = (const float*)d_in[9];
    const float* wc2    = (const float*)d_in[10];
    const float* wc3    = (const float*)d_in[11];
    float* out = (float*)d_out;
    const int npts = in_sizes[0] / 3;

    const size_t tp_bytes = (size_t)3 * 256 * 256 * 32 * 2;   // 12.58 MB planes
    const size_t pack_bytes = 28 * 1024;                      // 28 KB weight frags
    if (ws_size >= tp_bytes + pack_bytes) {
        unsigned int* tp_ws   = (unsigned int*)d_ws;
        unsigned int* pack_ws = (unsigned int*)((char*)d_ws + tp_bytes);
        transpose_planes_kernel<<<3072, 256, 0, stream>>>(pxy, pxz, pyz, tp_ws);
        pack_weights_kernel<<<7, 256, 0, stream>>>(w1, w2, wc1, wc2, wc3, pack_ws);
        const int nwt = (npts + 15) / 16;
        nerf_mfma_kernel<<<512, 512, 0, stream>>>(
            x, (const unsigned short*)tp_ws, pack_ws, center, scale, out, npts, nwt);
    } else {
        nerf_fallback_kernel<<<(npts + 255) / 256, 256, 0, stream>>>(
            x, pxy, pxz, pyz, center, scale, w1, w2, wc1, wc2, wc3, out, npts);
    }
}

// Round 7
// 192.145 us; speedup vs baseline: 1.0048x; 1.0048x over previous
//
#include <hip/hip_runtime.h>
#include <stdint.h>

typedef __attribute__((ext_vector_type(8))) unsigned short ushort8v;
typedef __attribute__((ext_vector_type(8))) short bf16x8;
typedef __attribute__((ext_vector_type(4))) float f32x4;
typedef __attribute__((ext_vector_type(2))) float f32x2;
typedef __attribute__((ext_vector_type(4))) unsigned int uint4v;

__device__ __forceinline__ float bf2f(unsigned short u) {
    return __uint_as_float(((unsigned)u) << 16);
}
__device__ __forceinline__ unsigned short f2bf(float f) {
    unsigned u = __float_as_uint(f);
    unsigned r = u + 0x7fffu + ((u >> 16) & 1u);   // RNE
    return (unsigned short)(r >> 16);
}
__device__ __forceinline__ unsigned cvt_pk_bf16(float lo, float hi) {
    unsigned r;
    asm("v_cvt_pk_bf16_f32 %0, %1, %2" : "=v"(r) : "v"(lo), "v"(hi));
    return r;
}
// unpack a bf16-pair word to two f32 (lo = <<16, hi = mask) — 2 VALU ops
__device__ __forceinline__ f32x2 up2(unsigned u) {
    f32x2 r;
    r[0] = __uint_as_float(u << 16);
    r[1] = __uint_as_float(u & 0xffff0000u);
    return r;
}

// ---------------- pre-pass 1: planes (3 x [32][256][256] f32) -> [3][y][x][c] bf16
__global__ __launch_bounds__(256) void transpose_planes_kernel(
    const float* __restrict__ pxy, const float* __restrict__ pxz,
    const float* __restrict__ pyz, unsigned int* __restrict__ tp)
{
    __shared__ unsigned int lt[64 * 17];   // [yx][c2], pad 17 kills bank conflicts
    const int bid = blockIdx.x;
    const int plane = bid >> 10;           // 1024 blocks per plane
    const int base = (bid & 1023) * 64;    // 64 pixels per block
    const float* __restrict__ src = plane == 0 ? pxy : (plane == 1 ? pxz : pyz);
    const int tid = threadIdx.x;
    {
        const int c2 = tid >> 4;           // channel pair 0..15
        const int s  = tid & 15;           // pixel group (4 px)
        const f32x4 va = *(const f32x4*)(src + (size_t)(2 * c2)     * 65536 + base + 4 * s);
        const f32x4 vb = *(const f32x4*)(src + (size_t)(2 * c2 + 1) * 65536 + base + 4 * s);
        #pragma unroll
        for (int j = 0; j < 4; ++j) {
            int yx = 4 * s + j;
            lt[yx * 17 + c2] = ((unsigned)f2bf(vb[j]) << 16) | (unsigned)f2bf(va[j]);
        }
    }
    __syncthreads();
    {
        const int yx = tid >> 2, q = tid & 3;
        uint4v o;
        #pragma unroll
        for (int k = 0; k < 4; ++k) o[k] = lt[yx * 17 + 4 * q + k];
        *(uint4v*)(tp + ((size_t)plane * 65536 + base + yx) * 16 + 4 * q) = o;
    }
}

// ---------------- pre-pass 2: pack MLP weights (transposed) into swizzled MFMA A-frag layout
// lane l's 16B at slot (l ^ (l>>3)); lane l holds A[mt*16+(l&15)][kc*32+(l>>4)*8+j].
__global__ __launch_bounds__(256) void pack_weights_kernel(
    const float* __restrict__ w1, const float* __restrict__ w2,
    const float* __restrict__ wc1, const float* __restrict__ wc2,
    const float* __restrict__ wc3, unsigned int* __restrict__ pack)
{
    int t = blockIdx.x * 256 + threadIdx.x;
    if (t >= 28 * 64) return;
    int lane = t & 63, tile = t >> 6;
    int mat, mt, kc;
    if (tile < 12)      { mat = 0; kc = tile >> 2;        mt = tile & 3; }
    else if (tile < 14) { mat = 1; kc = tile - 12;        mt = 0; }
    else if (tile < 18) { mat = 2; kc = 0;                mt = tile - 14; }
    else if (tile < 26) { mat = 3; kc = (tile - 18) >> 2; mt = (tile - 18) & 3; }
    else                { mat = 4; kc = tile - 26;        mt = 0; }
    int of = mt * 16 + (lane & 15);
    int kb = kc * 32 + (lane >> 4) * 8;
    float f[8];
    #pragma unroll
    for (int j = 0; j < 8; ++j) {
        int k = kb + j;
        float v;
        if (mat == 0)      v = w1[k * 64 + of];
        else if (mat == 1) v = w2[k * 16 + of];
        else if (mat == 2) v = (k >= 1 && k < 16) ? wc1[(k - 1) * 64 + of] : 0.0f;
        else if (mat == 3) v = wc2[k * 64 + of];
        else               v = (of < 3) ? wc3[k * 3 + of] : 0.0f;
        f[j] = v;
    }
    int sl = lane ^ (lane >> 3);
    unsigned int* dst = pack + tile * 256 + sl * 4;
    #pragma unroll
    for (int w = 0; w < 4; ++w)
        dst[w] = ((unsigned)f2bf(f[2 * w + 1]) << 16) | (unsigned)f2bf(f[2 * w]);
}

// ---------------- main: 2 wave-tiles (32 points) per wave, interleaved for ILP.
// Grid 1024 x 512: 4 blocks/CU (32 waves/CU) — ILP *and* TLP. 4 iters/block exactly.
__global__ __launch_bounds__(512, 4) void nerf_mfma_kernel(
    const float* __restrict__ xin,
    const unsigned short* __restrict__ tp,
    const unsigned int* __restrict__ wpack,
    const float* __restrict__ center, const float* __restrict__ scale,
    float* __restrict__ out, int npts, int nwt)
{
    __shared__ unsigned int wlds[28 * 256];
    const int tid = threadIdx.x;
    #pragma unroll 2
    for (int idx = tid; idx < 28 * 256; idx += 512) wlds[idx] = wpack[idx];
    __syncthreads();

    const int lane = tid & 63;
    const int wv   = tid >> 6;            // 0..7
    const int p    = lane & 15;
    const int G    = lane >> 4;
    const bool hi32 = (lane & 32) != 0;
    const int sl   = lane ^ (lane >> 3);
    const bf16x8* Af = (const bf16x8*)wlds;
    const char* tpB = (const char*)tp;

    const float ctr0 = center[0], ctr1 = center[1], ctr2 = center[2];
    const float sc0 = scale[0], sc1 = scale[1], sc2 = scale[2];

    auto repack64 = [&](const unsigned pk[4][2], int kc2) -> bf16x8 {
        uint4v bw;
        #pragma unroll
        for (int w = 0; w < 4; ++w) {
            int src = p + 16 * (2 * (G & 1) + (w >> 1));
            unsigned lo_ = (unsigned)__shfl((int)pk[2 * kc2][w & 1], src, 64);
            unsigned hi_ = (unsigned)__shfl((int)pk[2 * kc2 + 1][w & 1], src, 64);
            bw[w] = hi32 ? hi_ : lo_;
        }
        return __builtin_bit_cast(bf16x8, bw);
    };

    for (int wtb = blockIdx.x * 16; wtb < nwt; wtb += gridDim.x * 16) {
        asm volatile("" ::: "memory");
        const int wt0 = wtb + wv * 2;
        int gpt[2]; bool valid[2];
        float us[2][3], vs[2][3];
        #pragma unroll
        for (int u = 0; u < 2; ++u) {
            const int wt = wt0 + u;
            gpt[u] = wt * 16 + p;
            valid[u] = (wt < nwt) && (gpt[u] < npts);
            const int rp = valid[u] ? gpt[u] : (npts - 1);
            const float xv = xin[3 * rp + 0], yv = xin[3 * rp + 1], zv = xin[3 * rp + 2];
            auto norm1 = [&](float v, float c, float s) {
                float xn = fminf(fmaxf((v - c) / s + 0.5f, 0.0f), 1.0f);
                return xn * 2.0f - 1.0f;
            };
            const float gx = norm1(xv, ctr0, sc0);
            const float gy = norm1(yv, ctr1, sc1);
            const float gz = norm1(zv, ctr2, sc2);
            us[u][0] = gx; us[u][1] = gx; us[u][2] = gy;
            vs[u][0] = gy; vs[u][1] = gz; vs[u][2] = gz;
        }

        // ---- L1: per plane, gather both tiles (8 loads in flight), interp, shared-frag MFMA
        f32x4 acc1[2][4];
        #pragma unroll
        for (int u = 0; u < 2; ++u)
            #pragma unroll
            for (int mt = 0; mt < 4; ++mt) acc1[u][mt] = f32x4{0.f, 0.f, 0.f, 0.f};

        #pragma unroll
        for (int pl = 0; pl < 3; ++pl) {
            uint4v cv[2][4];
            float wq[2][4];
            #pragma unroll
            for (int u = 0; u < 2; ++u) {
                // px,py in [0,255] exactly (inputs pre-clipped) -> no clamps needed;
                // x1/y1 are +64B / +16KB offsets; boundary over-reads hit allocated ws
                // and carry an exactly-zero bilinear weight.
                float pxf = (us[u][pl] + 1.0f) * 0.5f * 255.0f;
                float pyf = (vs[u][pl] + 1.0f) * 0.5f * 255.0f;
                int x0 = (int)pxf, y0 = (int)pyf;
                float wx = pxf - (float)x0, wy = pyf - (float)y0;
                wq[u][0] = (1.f - wx) * (1.f - wy); wq[u][1] = wx * (1.f - wy);
                wq[u][2] = (1.f - wx) * wy;         wq[u][3] = wx * wy;
                const char* b00 = tpB + (((pl << 16) + (y0 << 8) + x0) << 6) + (G << 4);
                cv[u][0] = *(const uint4v*)(b00);
                cv[u][1] = *(const uint4v*)(b00 + 64);
                cv[u][2] = *(const uint4v*)(b00 + 16384);
                cv[u][3] = *(const uint4v*)(b00 + 16384 + 64);
            }
            bf16x8 bfr[2];
            #pragma unroll
            for (int u = 0; u < 2; ++u) {
                const f32x2 W00 = {wq[u][0], wq[u][0]}, W01 = {wq[u][1], wq[u][1]};
                const f32x2 W10 = {wq[u][2], wq[u][2]}, W11 = {wq[u][3], wq[u][3]};
                uint4v bw;
                #pragma unroll
                for (int w = 0; w < 4; ++w) {
                    f32x2 a = up2(cv[u][0][w]) * W00 + up2(cv[u][1][w]) * W01
                            + up2(cv[u][2][w]) * W10 + up2(cv[u][3][w]) * W11;
                    bw[w] = cvt_pk_bf16(a[0], a[1]);
                }
                bfr[u] = __builtin_bit_cast(bf16x8, bw);
            }
            #pragma unroll
            for (int mt = 0; mt < 4; ++mt) {
                const bf16x8 frag = Af[(pl * 4 + mt) * 64 + sl];
                #pragma unroll
                for (int u = 0; u < 2; ++u)
                    acc1[u][mt] = __builtin_amdgcn_mfma_f32_16x16x32_bf16(
                        frag, bfr[u], acc1[u][mt], 0, 0, 0);
            }
        }

        // ---- repack h (relu); L2: o^T = W2^T @ h^T
        unsigned pk1[2][4][2];
        #pragma unroll
        for (int u = 0; u < 2; ++u)
            #pragma unroll
            for (int mt = 0; mt < 4; ++mt) {
                pk1[u][mt][0] = cvt_pk_bf16(fmaxf(acc1[u][mt][0], 0.f), fmaxf(acc1[u][mt][1], 0.f));
                pk1[u][mt][1] = cvt_pk_bf16(fmaxf(acc1[u][mt][2], 0.f), fmaxf(acc1[u][mt][3], 0.f));
            }
        f32x4 acc2[2];
        #pragma unroll
        for (int u = 0; u < 2; ++u) acc2[u] = f32x4{0.f, 0.f, 0.f, 0.f};
        #pragma unroll
        for (int kc2 = 0; kc2 < 2; ++kc2) {
            bf16x8 b[2];
            #pragma unroll
            for (int u = 0; u < 2; ++u) b[u] = repack64(pk1[u], kc2);
            const bf16x8 frag = Af[(12 + kc2) * 64 + sl];
            #pragma unroll
            for (int u = 0; u < 2; ++u)
                acc2[u] = __builtin_amdgcn_mfma_f32_16x16x32_bf16(frag, b[u], acc2[u], 0, 0, 0);
        }
        #pragma unroll
        for (int u = 0; u < 2; ++u)
            if (valid[u] && lane < 16) out[(size_t)3 * npts + gpt[u]] = acc2[u][0];   // sigma

        // ---- repack o -> b3 (no relu; zero weight row kills sigma term); L3
        bf16x8 b3[2];
        #pragma unroll
        for (int u = 0; u < 2; ++u) {
            unsigned pk2[2];
            pk2[0] = cvt_pk_bf16(acc2[u][0], acc2[u][1]);
            pk2[1] = cvt_pk_bf16(acc2[u][2], acc2[u][3]);
            uint4v bw3;
            #pragma unroll
            for (int w = 0; w < 4; ++w) {
                int src = p + 16 * (2 * (G & 1) + (w >> 1));
                unsigned v = (unsigned)__shfl((int)pk2[w & 1], src, 64);
                bw3[w] = (G < 2) ? v : 0u;
            }
            b3[u] = __builtin_bit_cast(bf16x8, bw3);
        }
        f32x4 acc3[2][4];
        #pragma unroll
        for (int u = 0; u < 2; ++u)
            #pragma unroll
            for (int mt = 0; mt < 4; ++mt) acc3[u][mt] = f32x4{0.f, 0.f, 0.f, 0.f};
        #pragma unroll
        for (int mt = 0; mt < 4; ++mt) {
            const bf16x8 frag = Af[(14 + mt) * 64 + sl];
            #pragma unroll
            for (int u = 0; u < 2; ++u)
                acc3[u][mt] = __builtin_amdgcn_mfma_f32_16x16x32_bf16(frag, b3[u], acc3[u][mt], 0, 0, 0);
        }

        // ---- repack c1 (relu); L4
        unsigned pk3[2][4][2];
        #pragma unroll
        for (int u = 0; u < 2; ++u)
            #pragma unroll
            for (int mt = 0; mt < 4; ++mt) {
                pk3[u][mt][0] = cvt_pk_bf16(fmaxf(acc3[u][mt][0], 0.f), fmaxf(acc3[u][mt][1], 0.f));
                pk3[u][mt][1] = cvt_pk_bf16(fmaxf(acc3[u][mt][2], 0.f), fmaxf(acc3[u][mt][3], 0.f));
            }
        f32x4 acc4[2][4];
        #pragma unroll
        for (int u = 0; u < 2; ++u)
            #pragma unroll
            for (int mt = 0; mt < 4; ++mt) acc4[u][mt] = f32x4{0.f, 0.f, 0.f, 0.f};
        #pragma unroll
        for (int kc2 = 0; kc2 < 2; ++kc2) {
            bf16x8 b[2];
            #pragma unroll
            for (int u = 0; u < 2; ++u) b[u] = repack64(pk3[u], kc2);
            #pragma unroll
            for (int mt = 0; mt < 4; ++mt) {
                const bf16x8 frag = Af[(18 + kc2 * 4 + mt) * 64 + sl];
                #pragma unroll
                for (int u = 0; u < 2; ++u)
                    acc4[u][mt] = __builtin_amdgcn_mfma_f32_16x16x32_bf16(frag, b[u], acc4[u][mt], 0, 0, 0);
            }
        }

        // ---- repack c2 (relu); L5: color^T = Wc3^T @ relu(c2)^T
        unsigned pk4[2][4][2];
        #pragma unroll
        for (int u = 0; u < 2; ++u)
            #pragma unroll
            for (int mt = 0; mt < 4; ++mt) {
                pk4[u][mt][0] = cvt_pk_bf16(fmaxf(acc4[u][mt][0], 0.f), fmaxf(acc4[u][mt][1], 0.f));
                pk4[u][mt][1] = cvt_pk_bf16(fmaxf(acc4[u][mt][2], 0.f), fmaxf(acc4[u][mt][3], 0.f));
            }
        f32x4 acc5[2];
        #pragma unroll
        for (int u = 0; u < 2; ++u) acc5[u] = f32x4{0.f, 0.f, 0.f, 0.f};
        #pragma unroll
        for (int kc2 = 0; kc2 < 2; ++kc2) {
            bf16x8 b[2];
            #pragma unroll
            for (int u = 0; u < 2; ++u) b[u] = repack64(pk4[u], kc2);
            const bf16x8 frag = Af[(26 + kc2) * 64 + sl];
            #pragma unroll
            for (int u = 0; u < 2; ++u)
                acc5[u] = __builtin_amdgcn_mfma_f32_16x16x32_bf16(frag, b[u], acc5[u], 0, 0, 0);
        }
        #pragma unroll
        for (int u = 0; u < 2; ++u)
            if (valid[u] && lane < 16) {
                out[(size_t)3 * gpt[u] + 0] = 1.0f / (1.0f + __expf(-acc5[u][0]));
                out[(size_t)3 * gpt[u] + 1] = 1.0f / (1.0f + __expf(-acc5[u][1]));
                out[(size_t)3 * gpt[u] + 2] = 1.0f / (1.0f + __expf(-acc5[u][2]));
            }
    }
}

// ---------------- fallback (ws too small): pure-VALU kernel, f32 planes
__global__ __launch_bounds__(256) void nerf_fallback_kernel(
    const float* __restrict__ xin,
    const float* __restrict__ pxy, const float* __restrict__ pxz,
    const float* __restrict__ pyz,
    const float* __restrict__ center, const float* __restrict__ scale,
    const float* __restrict__ w1, const float* __restrict__ w2,
    const float* __restrict__ wc1, const float* __restrict__ wc2,
    const float* __restrict__ wc3, float* __restrict__ out, int npts)
{
    __shared__ unsigned short act[64][256];
    const int tid = threadIdx.x;
    const int i = blockIdx.x * 256 + tid;
    if (i >= npts) return;
    const float xv = xin[3 * i], yv = xin[3 * i + 1], zv = xin[3 * i + 2];
    auto norm1 = [&](float v, int k) {
        float xn = fminf(fmaxf((v - center[k]) / scale[k] + 0.5f, 0.0f), 1.0f);
        return xn * 2.0f - 1.0f;
    };
    const float gx = norm1(xv, 0), gy = norm1(yv, 1), gz = norm1(zv, 2);
    float h[64];
    #pragma unroll
    for (int j = 0; j < 64; ++j) h[j] = 0.0f;
    auto samp = [&](float gu, float gv, int pl, const float* __restrict__ splane) {
        float pxf = (gu + 1.0f) * 0.5f * 255.0f, pyf = (gv + 1.0f) * 0.5f * 255.0f;
        float x0f = floorf(pxf), y0f = floorf(pyf);
        float wx = pxf - x0f, wy = pyf - y0f;
        int x0 = min(max((int)x0f, 0), 255), y0 = min(max((int)y0f, 0), 255);
        int x1 = min(x0 + 1, 255), y1 = min(y0 + 1, 255);
        float w00 = (1 - wx) * (1 - wy), w01 = wx * (1 - wy), w10 = (1 - wx) * wy, w11 = wx * wy;
        for (int c = 0; c < 32; ++c) {
            const float* b = splane + (size_t)c * 65536;
            float f = b[y0 * 256 + x0] * w00 + b[y0 * 256 + x1] * w01
                    + b[y1 * 256 + x0] * w10 + b[y1 * 256 + x1] * w11;
            const float* wr = w1 + (size_t)((pl * 32 + c) * 64);
            #pragma unroll
            for (int j = 0; j < 64; ++j) h[j] = fmaf(f, wr[j], h[j]);
        }
    };
    samp(gx, gy, 0, pxy); samp(gx, gz, 1, pxz); samp(gy, gz, 2, pyz);
    #pragma unroll
    for (int j = 0; j < 64; ++j) act[j][tid] = f2bf(fmaxf(h[j], 0.0f));
    float o[16];
    #pragma unroll
    for (int j = 0; j < 16; ++j) o[j] = 0.0f;
    for (int k = 0; k < 64; ++k) {
        float hv = bf2f(act[k][tid]);
        #pragma unroll
        for (int j = 0; j < 16; ++j) o[j] = fmaf(hv, w2[k * 16 + j], o[j]);
    }
    out[(size_t)3 * npts + i] = o[0];
    float c1[64];
    #pragma unroll
    for (int j = 0; j < 64; ++j) c1[j] = 0.0f;
    #pragma unroll
    for (int k = 0; k < 15; ++k)
        #pragma unroll
        for (int j = 0; j < 64; ++j) c1[j] = fmaf(o[k + 1], wc1[k * 64 + j], c1[j]);
    #pragma unroll
    for (int j = 0; j < 64; ++j) act[j][tid] = f2bf(fmaxf(c1[j], 0.0f));
    float c2[64];
    #pragma unroll
    for (int j = 0; j < 64; ++j) c2[j] = 0.0f;
    for (int k = 0; k < 64; ++k) {
        float v = bf2f(act[k][tid]);
        #pragma unroll
        for (int j = 0; j < 64; ++j) c2[j] = fmaf(v, wc2[k * 64 + j], c2[j]);
    }
    float r0 = 0, r1 = 0, r2 = 0;
    #pragma unroll
    for (int k = 0; k < 64; ++k) {
        float v = fmaxf(c2[k], 0.0f);
        r0 = fmaf(v, wc3[k * 3 + 0], r0);
        r1 = fmaf(v, wc3[k * 3 + 1], r1);
        r2 = fmaf(v, wc3[k * 3 + 2], r2);
    }
    out[(size_t)3 * i + 0] = 1.0f / (1.0f + expf(-r0));
    out[(size_t)3 * i + 1] = 1.0f / (1.0f + expf(-r1));
    out[(size_t)3 * i + 2] = 1.0f / (1.0f + expf(-r2));
}

extern "C" void kernel_launch(void* const* d_in, const int* in_sizes, int n_in,
                              void* d_out, int out_size, void* d_ws, size_t ws_size,
                              hipStream_t stream) {
    const float* x      = (const float*)d_in[0];
    const float* pxy    = (const float*)d_in[2];
    const float* pxz    = (const float*)d_in[3];
    const float* pyz    = (const float*)d_in[4];
    const float* center = (const float*)d_in[5];
    const float* scale  = (const float*)d_in[6];
    const float* w1     = (const float*)d_in[7];
    const float* w2     = (const float*)d_in[8];
    const float* wc1    = (const float*)d_in[9];
    const float* wc2    = (const float*)d_in[10];
    const float* wc3    = (const float*)d_in[11];
    float* out = (float*)d_out;
    const int npts = in_sizes[0] / 3;

    const size_t tp_bytes = (size_t)3 * 256 * 256 * 32 * 2;   // 12.58 MB planes
    const size_t pack_bytes = 28 * 1024;                      // 28 KB weight frags
    if (ws_size >= tp_bytes + pack_bytes) {
        unsigned int* tp_ws   = (unsigned int*)d_ws;
        unsigned int* pack_ws = (unsigned int*)((char*)d_ws + tp_bytes);
        transpose_planes_kernel<<<3072, 256, 0, stream>>>(pxy, pxz, pyz, tp_ws);
        pack_weights_kernel<<<7, 256, 0, stream>>>(w1, w2, wc1, wc2, wc3, pack_ws);
        const int nwt = (npts + 15) / 16;
        // 1024 blocks x 512 thr = 4 blocks/CU (LDS allows 5): ILP from 2-tile pairs
        // AND full TLP. nwt=65536 -> exactly 4 grid-stride iterations per block.
        nerf_mfma_kernel<<<1024, 512, 0, stream>>>(
            x, (const unsigned short*)tp_ws, pack_ws, center, scale, out, npts, nwt);
    } else {
        nerf_fallback_kernel<<<(npts + 255) / 256, 256, 0, stream>>>(
            x, pxy, pxz, pyz, center, scale, w1, w2, wc1, wc2, wc3, out, npts);
    }
}

// Round 9
// 186.243 us; speedup vs baseline: 1.0366x; 1.0317x over previous
//
#include <hip/hip_runtime.h>
#include <stdint.h>

typedef __attribute__((ext_vector_type(8))) unsigned short ushort8v;
typedef __attribute__((ext_vector_type(8))) short bf16x8;
typedef __attribute__((ext_vector_type(4))) float f32x4;
typedef __attribute__((ext_vector_type(2))) float f32x2;
typedef __attribute__((ext_vector_type(4))) unsigned int uint4v;

__device__ __forceinline__ float bf2f(unsigned short u) {
    return __uint_as_float(((unsigned)u) << 16);
}
__device__ __forceinline__ unsigned short f2bf(float f) {
    unsigned u = __float_as_uint(f);
    unsigned r = u + 0x7fffu + ((u >> 16) & 1u);   // RNE
    return (unsigned short)(r >> 16);
}
__device__ __forceinline__ unsigned cvt_pk_bf16(float lo, float hi) {
    unsigned r;
    asm("v_cvt_pk_bf16_f32 %0, %1, %2" : "=v"(r) : "v"(lo), "v"(hi));
    return r;
}
// unpack a bf16-pair word to two f32
__device__ __forceinline__ f32x2 up2(unsigned u) {
    f32x2 r;
    r[0] = __uint_as_float(u << 16);
    r[1] = __uint_as_float(u & 0xffff0000u);
    return r;
}
// k-permutation: B-frag slot k' = kc2*32 + G*8 + j  <-  activation index
// pi(k') = (j>>1)*16 + G*4 + (j&1) + 2*kc2.  Bijection on [0,64).
// With next-layer weights packed as A'[o][k'] = W[pi(k')][o], the B-frag at
// lane (G,p) is exactly the lane's own cvt_pk words: bw[w] = pk[w][kc2].
__device__ __forceinline__ int pi64(int k) {
    int G = (k >> 3) & 3, j = k & 7, kc2 = k >> 5;
    return ((j >> 1) << 4) + (G << 2) + (j & 1) + (kc2 << 1);
}

// ---------------- pre-pass 1: planes (3 x [32][256][256] f32) -> [3][y][x][c] bf16
__global__ __launch_bounds__(256) void transpose_planes_kernel(
    const float* __restrict__ pxy, const float* __restrict__ pxz,
    const float* __restrict__ pyz, unsigned int* __restrict__ tp)
{
    __shared__ unsigned int lt[64 * 17];
    const int bid = blockIdx.x;
    const int plane = bid >> 10;
    const int base = (bid & 1023) * 64;
    const float* __restrict__ src = plane == 0 ? pxy : (plane == 1 ? pxz : pyz);
    const int tid = threadIdx.x;
    {
        const int c2 = tid >> 4;
        const int s  = tid & 15;
        const f32x4 va = *(const f32x4*)(src + (size_t)(2 * c2)     * 65536 + base + 4 * s);
        const f32x4 vb = *(const f32x4*)(src + (size_t)(2 * c2 + 1) * 65536 + base + 4 * s);
        #pragma unroll
        for (int j = 0; j < 4; ++j) {
            int yx = 4 * s + j;
            lt[yx * 17 + c2] = ((unsigned)f2bf(vb[j]) << 16) | (unsigned)f2bf(va[j]);
        }
    }
    __syncthreads();
    {
        const int yx = tid >> 2, q = tid & 3;
        uint4v o;
        #pragma unroll
        for (int k = 0; k < 4; ++k) o[k] = lt[yx * 17 + 4 * q + k];
        *(uint4v*)(tp + ((size_t)plane * 65536 + base + yx) * 16 + 4 * q) = o;
    }
}

// ---------------- pre-pass 2: pack MLP weights into swizzled MFMA A-frag layout,
// with the pi64 k-permutation baked into L2/L4/L5 (and the L3 K=32 padded map).
//  L1: w1^T [64x96]              tiles 0..11  (kc*4+mt)   k unpermuted
//  L2: w2^T [16x64]  k'=pi64     tiles 12..13 (kc)
//  L3: wc1  [64x32]  k'=G*8+j -> (j<4 ? o=G*4+j : zero); o==0 row zero (sigma)
//                                tiles 14..17 (mt)
//  L4: wc2^T [64x64] k'=pi64     tiles 18..25 (kc*4+mt)
//  L5: wc3^T [16x64] k'=pi64, of<3 else 0   tiles 26..27 (kc)
__global__ __launch_bounds__(256) void pack_weights_kernel(
    const float* __restrict__ w1, const float* __restrict__ w2,
    const float* __restrict__ wc1, const float* __restrict__ wc2,
    const float* __restrict__ wc3, unsigned int* __restrict__ pack)
{
    int t = blockIdx.x * 256 + threadIdx.x;
    if (t >= 28 * 64) return;
    int lane = t & 63, tile = t >> 6;
    int mat, mt, kc;
    if (tile < 12)      { mat = 0; kc = tile >> 2;        mt = tile & 3; }
    else if (tile < 14) { mat = 1; kc = tile - 12;        mt = 0; }
    else if (tile < 18) { mat = 2; kc = 0;                mt = tile - 14; }
    else if (tile < 26) { mat = 3; kc = (tile - 18) >> 2; mt = (tile - 18) & 3; }
    else                { mat = 4; kc = tile - 26;        mt = 0; }
    int of = mt * 16 + (lane & 15);
    int kb = kc * 32 + (lane >> 4) * 8;
    float f[8];
    #pragma unroll
    for (int j = 0; j < 8; ++j) {
        int k = kb + j;
        float v;
        if (mat == 0)      v = w1[k * 64 + of];
        else if (mat == 1) v = w2[pi64(k) * 16 + of];
        else if (mat == 2) {
            int jj = k & 7, Gk = (k >> 3) & 3;
            if (jj < 4) {
                int ke = Gk * 4 + jj;                 // o-index 0..15; 0 = sigma -> zero
                v = (ke >= 1) ? wc1[(ke - 1) * 64 + of] : 0.0f;
            } else v = 0.0f;
        }
        else if (mat == 3) v = wc2[pi64(k) * 64 + of];
        else               v = (of < 3) ? wc3[pi64(k) * 3 + of] : 0.0f;
        f[j] = v;
    }
    int sl = lane ^ (lane >> 3);
    unsigned int* dst = pack + tile * 256 + sl * 4;
    #pragma unroll
    for (int w = 0; w < 4; ++w)
        dst[w] = ((unsigned)f2bf(f[2 * w + 1]) << 16) | (unsigned)f2bf(f[2 * w]);
}

// ---------------- main: 2 wave-tiles (32 points) per wave; ZERO-shuffle layer chain.
// C-layout -> next B-frag is a pure register reinterpret (pi64-permuted weights).
__global__ __launch_bounds__(512) void nerf_mfma_kernel(
    const float* __restrict__ xin,
    const unsigned short* __restrict__ tp,
    const unsigned int* __restrict__ wpack,
    const float* __restrict__ center, const float* __restrict__ scale,
    float* __restrict__ out, int npts, int nwt)
{
    __shared__ unsigned int wlds[28 * 256];
    const int tid = threadIdx.x;
    #pragma unroll 2
    for (int idx = tid; idx < 28 * 256; idx += 512) wlds[idx] = wpack[idx];
    __syncthreads();

    const int lane = tid & 63;
    const int wv   = tid >> 6;
    const int p    = lane & 15;
    const int G    = lane >> 4;
    const int sl   = lane ^ (lane >> 3);
    const bf16x8* Af = (const bf16x8*)wlds;
    const char* tpB = (const char*)tp;

    const float ctr0 = center[0], ctr1 = center[1], ctr2 = center[2];
    const float sc0 = scale[0], sc1 = scale[1], sc2 = scale[2];

    for (int wtb = blockIdx.x * 16; wtb < nwt; wtb += gridDim.x * 16) {
        asm volatile("" ::: "memory");
        const int wt0 = wtb + wv * 2;
        int gpt[2]; bool valid[2];
        float us[2][3], vs[2][3];
        #pragma unroll
        for (int u = 0; u < 2; ++u) {
            const int wt = wt0 + u;
            gpt[u] = wt * 16 + p;
            valid[u] = (wt < nwt) && (gpt[u] < npts);
            const int rp = valid[u] ? gpt[u] : (npts - 1);
            const float xv = xin[3 * rp + 0], yv = xin[3 * rp + 1], zv = xin[3 * rp + 2];
            auto norm1 = [&](float v, float c, float s) {
                float xn = fminf(fmaxf((v - c) / s + 0.5f, 0.0f), 1.0f);
                return xn * 2.0f - 1.0f;
            };
            const float gx = norm1(xv, ctr0, sc0);
            const float gy = norm1(yv, ctr1, sc1);
            const float gz = norm1(zv, ctr2, sc2);
            us[u][0] = gx; us[u][1] = gx; us[u][2] = gy;
            vs[u][0] = gy; vs[u][1] = gz; vs[u][2] = gz;
        }

        // ---- L1: gather + bilinear interp feeds B-frags natively
        f32x4 acc1[2][4];
        #pragma unroll
        for (int u = 0; u < 2; ++u)
            #pragma unroll
            for (int mt = 0; mt < 4; ++mt) acc1[u][mt] = f32x4{0.f, 0.f, 0.f, 0.f};

        #pragma unroll
        for (int pl = 0; pl < 3; ++pl) {
            uint4v cv[2][4];
            float wq[2][4];
            #pragma unroll
            for (int u = 0; u < 2; ++u) {
                float pxf = (us[u][pl] + 1.0f) * 0.5f * 255.0f;
                float pyf = (vs[u][pl] + 1.0f) * 0.5f * 255.0f;
                int x0 = (int)pxf, y0 = (int)pyf;
                float wx = pxf - (float)x0, wy = pyf - (float)y0;
                wq[u][0] = (1.f - wx) * (1.f - wy); wq[u][1] = wx * (1.f - wy);
                wq[u][2] = (1.f - wx) * wy;         wq[u][3] = wx * wy;
                const char* b00 = tpB + (((pl << 16) + (y0 << 8) + x0) << 6) + (G << 4);
                cv[u][0] = *(const uint4v*)(b00);
                cv[u][1] = *(const uint4v*)(b00 + 64);
                cv[u][2] = *(const uint4v*)(b00 + 16384);
                cv[u][3] = *(const uint4v*)(b00 + 16384 + 64);
            }
            bf16x8 bfr[2];
            #pragma unroll
            for (int u = 0; u < 2; ++u) {
                const f32x2 W00 = {wq[u][0], wq[u][0]}, W01 = {wq[u][1], wq[u][1]};
                const f32x2 W10 = {wq[u][2], wq[u][2]}, W11 = {wq[u][3], wq[u][3]};
                uint4v bw;
                #pragma unroll
                for (int w = 0; w < 4; ++w) {
                    f32x2 a = up2(cv[u][0][w]) * W00 + up2(cv[u][1][w]) * W01
                            + up2(cv[u][2][w]) * W10 + up2(cv[u][3][w]) * W11;
                    bw[w] = cvt_pk_bf16(a[0], a[1]);
                }
                bfr[u] = __builtin_bit_cast(bf16x8, bw);
            }
            #pragma unroll
            for (int mt = 0; mt < 4; ++mt) {
                const bf16x8 frag = Af[(pl * 4 + mt) * 64 + sl];
                #pragma unroll
                for (int u = 0; u < 2; ++u)
                    acc1[u][mt] = __builtin_amdgcn_mfma_f32_16x16x32_bf16(
                        frag, bfr[u], acc1[u][mt], 0, 0, 0);
            }
        }

        // ---- h: relu + pack; B-frag(kc2) = {pk1[0..3][kc2]} — no shuffles
        unsigned pk1[2][4][2];
        #pragma unroll
        for (int u = 0; u < 2; ++u)
            #pragma unroll
            for (int mt = 0; mt < 4; ++mt) {
                pk1[u][mt][0] = cvt_pk_bf16(fmaxf(acc1[u][mt][0], 0.f), fmaxf(acc1[u][mt][1], 0.f));
                pk1[u][mt][1] = cvt_pk_bf16(fmaxf(acc1[u][mt][2], 0.f), fmaxf(acc1[u][mt][3], 0.f));
            }
        f32x4 acc2[2];
        #pragma unroll
        for (int u = 0; u < 2; ++u) acc2[u] = f32x4{0.f, 0.f, 0.f, 0.f};
        #pragma unroll
        for (int kc2 = 0; kc2 < 2; ++kc2) {
            const bf16x8 frag = Af[(12 + kc2) * 64 + sl];
            #pragma unroll
            for (int u = 0; u < 2; ++u) {
                uint4v bw = {pk1[u][0][kc2], pk1[u][1][kc2], pk1[u][2][kc2], pk1[u][3][kc2]};
                acc2[u] = __builtin_amdgcn_mfma_f32_16x16x32_bf16(
                    frag, __builtin_bit_cast(bf16x8, bw), acc2[u], 0, 0, 0);
            }
        }
        #pragma unroll
        for (int u = 0; u < 2; ++u)
            if (valid[u] && lane < 16) out[(size_t)3 * npts + gpt[u]] = acc2[u][0];   // sigma

        // ---- o -> b3 = {pk2[0], pk2[1], 0, 0} (weights already o-mapped + sigma-zeroed)
        f32x4 acc3[2][4];
        #pragma unroll
        for (int u = 0; u < 2; ++u)
            #pragma unroll
            for (int mt = 0; mt < 4; ++mt) acc3[u][mt] = f32x4{0.f, 0.f, 0.f, 0.f};
        bf16x8 b3[2];
        #pragma unroll
        for (int u = 0; u < 2; ++u) {
            uint4v bw3 = {cvt_pk_bf16(acc2[u][0], acc2[u][1]),
                          cvt_pk_bf16(acc2[u][2], acc2[u][3]), 0u, 0u};
            b3[u] = __builtin_bit_cast(bf16x8, bw3);
        }
        #pragma unroll
        for (int mt = 0; mt < 4; ++mt) {
            const bf16x8 frag = Af[(14 + mt) * 64 + sl];
            #pragma unroll
            for (int u = 0; u < 2; ++u)
                acc3[u][mt] = __builtin_amdgcn_mfma_f32_16x16x32_bf16(frag, b3[u], acc3[u][mt], 0, 0, 0);
        }

        // ---- c1: relu + pack; L4
        unsigned pk3[2][4][2];
        #pragma unroll
        for (int u = 0; u < 2; ++u)
            #pragma unroll
            for (int mt = 0; mt < 4; ++mt) {
                pk3[u][mt][0] = cvt_pk_bf16(fmaxf(acc3[u][mt][0], 0.f), fmaxf(acc3[u][mt][1], 0.f));
                pk3[u][mt][1] = cvt_pk_bf16(fmaxf(acc3[u][mt][2], 0.f), fmaxf(acc3[u][mt][3], 0.f));
            }
        f32x4 acc4[2][4];
        #pragma unroll
        for (int u = 0; u < 2; ++u)
            #pragma unroll
            for (int mt = 0; mt < 4; ++mt) acc4[u][mt] = f32x4{0.f, 0.f, 0.f, 0.f};
        #pragma unroll
        for (int kc2 = 0; kc2 < 2; ++kc2) {
            #pragma unroll
            for (int mt = 0; mt < 4; ++mt) {
                const bf16x8 frag = Af[(18 + kc2 * 4 + mt) * 64 + sl];
                #pragma unroll
                for (int u = 0; u < 2; ++u) {
                    uint4v bw = {pk3[u][0][kc2], pk3[u][1][kc2], pk3[u][2][kc2], pk3[u][3][kc2]};
                    acc4[u][mt] = __builtin_amdgcn_mfma_f32_16x16x32_bf16(
                        frag, __builtin_bit_cast(bf16x8, bw), acc4[u][mt], 0, 0, 0);
                }
            }
        }

        // ---- c2: relu + pack; L5
        unsigned pk4[2][4][2];
        #pragma unroll
        for (int u = 0; u < 2; ++u)
            #pragma unroll
            for (int mt = 0; mt < 4; ++mt) {
                pk4[u][mt][0] = cvt_pk_bf16(fmaxf(acc4[u][mt][0], 0.f), fmaxf(acc4[u][mt][1], 0.f));
                pk4[u][mt][1] = cvt_pk_bf16(fmaxf(acc4[u][mt][2], 0.f), fmaxf(acc4[u][mt][3], 0.f));
            }
        f32x4 acc5[2];
        #pragma unroll
        for (int u = 0; u < 2; ++u) acc5[u] = f32x4{0.f, 0.f, 0.f, 0.f};
        #pragma unroll
        for (int kc2 = 0; kc2 < 2; ++kc2) {
            const bf16x8 frag = Af[(26 + kc2) * 64 + sl];
            #pragma unroll
            for (int u = 0; u < 2; ++u) {
                uint4v bw = {pk4[u][0][kc2], pk4[u][1][kc2], pk4[u][2][kc2], pk4[u][3][kc2]};
                acc5[u] = __builtin_amdgcn_mfma_f32_16x16x32_bf16(
                    frag, __builtin_bit_cast(bf16x8, bw), acc5[u], 0, 0, 0);
            }
        }
        #pragma unroll
        for (int u = 0; u < 2; ++u)
            if (valid[u] && lane < 16) {
                out[(size_t)3 * gpt[u] + 0] = 1.0f / (1.0f + __expf(-acc5[u][0]));
                out[(size_t)3 * gpt[u] + 1] = 1.0f / (1.0f + __expf(-acc5[u][1]));
                out[(size_t)3 * gpt[u] + 2] = 1.0f / (1.0f + __expf(-acc5[u][2]));
            }
    }
}

// ---------------- fallback (ws too small): pure-VALU kernel, f32 planes
__global__ __launch_bounds__(256) void nerf_fallback_kernel(
    const float* __restrict__ xin,
    const float* __restrict__ pxy, const float* __restrict__ pxz,
    const float* __restrict__ pyz,
    const float* __restrict__ center, const float* __restrict__ scale,
    const float* __restrict__ w1, const float* __restrict__ w2,
    const float* __restrict__ wc1, const float* __restrict__ wc2,
    const float* __restrict__ wc3, float* __restrict__ out, int npts)
{
    __shared__ unsigned short act[64][256];
    const int tid = threadIdx.x;
    const int i = blockIdx.x * 256 + tid;
    if (i >= npts) return;
    const float xv = xin[3 * i], yv = xin[3 * i + 1], zv = xin[3 * i + 2];
    auto norm1 = [&](float v, int k) {
        float xn = fminf(fmaxf((v - center[k]) / scale[k] + 0.5f, 0.0f), 1.0f);
        return xn * 2.0f - 1.0f;
    };
    const float gx = norm1(xv, 0), gy = norm1(yv, 1), gz = norm1(zv, 2);
    float h[64];
    #pragma unroll
    for (int j = 0; j < 64; ++j) h[j] = 0.0f;
    auto samp = [&](float gu, float gv, int pl, const float* __restrict__ splane) {
        float pxf = (gu + 1.0f) * 0.5f * 255.0f, pyf = (gv + 1.0f) * 0.5f * 255.0f;
        float x0f = floorf(pxf), y0f = floorf(pyf);
        float wx = pxf - x0f, wy = pyf - y0f;
        int x0 = min(max((int)x0f, 0), 255), y0 = min(max((int)y0f, 0), 255);
        int x1 = min(x0 + 1, 255), y1 = min(y0 + 1, 255);
        float w00 = (1 - wx) * (1 - wy), w01 = wx * (1 - wy), w10 = (1 - wx) * wy, w11 = wx * wy;
        for (int c = 0; c < 32; ++c) {
            const float* b = splane + (size_t)c * 65536;
            float f = b[y0 * 256 + x0] * w00 + b[y0 * 256 + x1] * w01
                    + b[y1 * 256 + x0] * w10 + b[y1 * 256 + x1] * w11;
            const float* wr = w1 + (size_t)((pl * 32 + c) * 64);
            #pragma unroll
            for (int j = 0; j < 64; ++j) h[j] = fmaf(f, wr[j], h[j]);
        }
    };
    samp(gx, gy, 0, pxy); samp(gx, gz, 1, pxz); samp(gy, gz, 2, pyz);
    #pragma unroll
    for (int j = 0; j < 64; ++j) act[j][tid] = f2bf(fmaxf(h[j], 0.0f));
    float o[16];
    #pragma unroll
    for (int j = 0; j < 16; ++j) o[j] = 0.0f;
    for (int k = 0; k < 64; ++k) {
        float hv = bf2f(act[k][tid]);
        #pragma unroll
        for (int j = 0; j < 16; ++j) o[j] = fmaf(hv, w2[k * 16 + j], o[j]);
    }
    out[(size_t)3 * npts + i] = o[0];
    float c1[64];
    #pragma unroll
    for (int j = 0; j < 64; ++j) c1[j] = 0.0f;
    #pragma unroll
    for (int k = 0; k < 15; ++k)
        #pragma unroll
        for (int j = 0; j < 64; ++j) c1[j] = fmaf(o[k + 1], wc1[k * 64 + j], c1[j]);
    #pragma unroll
    for (int j = 0; j < 64; ++j) act[j][tid] = f2bf(fmaxf(c1[j], 0.0f));
    float c2[64];
    #pragma unroll
    for (int j = 0; j < 64; ++j) c2[j] = 0.0f;
    for (int k = 0; k < 64; ++k) {
        float v = bf2f(act[k][tid]);
        #pragma unroll
        for (int j = 0; j < 64; ++j) c2[j] = fmaf(v, wc2[k * 64 + j], c2[j]);
    }
    float r0 = 0, r1 = 0, r2 = 0;
    #pragma unroll
    for (int k = 0; k < 64; ++k) {
        float v = fmaxf(c2[k], 0.0f);
        r0 = fmaf(v, wc3[k * 3 + 0], r0);
        r1 = fmaf(v, wc3[k * 3 + 1], r1);
        r2 = fmaf(v, wc3[k * 3 + 2], r2);
    }
    out[(size_t)3 * i + 0] = 1.0f / (1.0f + expf(-r0));
    out[(size_t)3 * i + 1] = 1.0f / (1.0f + expf(-r1));
    out[(size_t)3 * i + 2] = 1.0f / (1.0f + expf(-r2));
}

extern "C" void kernel_launch(void* const* d_in, const int* in_sizes, int n_in,
                              void* d_out, int out_size, void* d_ws, size_t ws_size,
                              hipStream_t stream) {
    const float* x      = (const float*)d_in[0];
    const float* pxy    = (const float*)d_in[2];
    const float* pxz    = (const float*)d_in[3];
    const float* pyz    = (const float*)d_in[4];
    const float* center = (const float*)d_in[5];
    const float* scale  = (const float*)d_in[6];
    const float* w1     = (const float*)d_in[7];
    const float* w2     = (const float*)d_in[8];
    const float* wc1    = (const float*)d_in[9];
    const float* wc2    = (const float*)d_in[10];
    const float* wc3    = (const float*)d_in[11];
    float* out = (float*)d_out;
    const int npts = in_sizes[0] / 3;

    const size_t tp_bytes = (size_t)3 * 256 * 256 * 32 * 2;   // 12.58 MB planes
    const size_t pack_bytes = 28 * 1024;                      // 28 KB weight frags
    if (ws_size >= tp_bytes + pack_bytes) {
        unsigned int* tp_ws   = (unsigned int*)d_ws;
        unsigned int* pack_ws = (unsigned int*)((char*)d_ws + tp_bytes);
        transpose_planes_kernel<<<3072, 256, 0, stream>>>(pxy, pxz, pyz, tp_ws);
        pack_weights_kernel<<<7, 256, 0, stream>>>(w1, w2, wc1, wc2, wc3, pack_ws);
        const int nwt = (npts + 15) / 16;
        nerf_mfma_kernel<<<1024, 512, 0, stream>>>(
            x, (const unsigned short*)tp_ws, pack_ws, center, scale, out, npts, nwt);
    } else {
        nerf_fallback_kernel<<<(npts + 255) / 256, 256, 0, stream>>>(
            x, pxy, pxz, pyz, center, scale, w1, w2, wc1, wc2, wc3, out, npts);
    }
}